// Round 12
// baseline (188.909 us; speedup 1.0000x reference)
//
#include <hip/hip_runtime.h>

// GNNCriticEncoder fused kernel v14 (MI355X / gfx950)
// v13 failed (absmax 0.29, race-signature like v8). Suspect set = its 3 novel pieces
// {sequential-j, barrier restructure, direct-global embed} -- not isolatable by
// inspection. v14 rebuilds from PROVEN pieces only:
//  - v12-proven: complement-pad + scatter (disjoint, one fence), ballot-mask softmax,
//    direct out stores. v11-proven: LDS-staged embed, acc-major GEMM, head-split PV.
//  - NEW (each individually fenced): persistent 2048 blocks with sequential j in-block
//    (barrier at j-top), separate s_h (no x<->hT alias; 18944 B LDS).
//  - 6 barriers/item (vs v11's 8), every s_x write<->read epoch pair fenced:
//    [barJ] pad+scatter [barS] Bxin reads [barX] embed writes [barG] GEMM reads
//    [barE, L0] x_next writes [barG] GEMM reads [barJ next j] ...
//  - direct-global embed EXCLUDED (v13's remaining suspect; A/B next round if green).
// ws = exactly 81920 B (do not exceed).

#define NTOK 32
#define EMB  128
#define OBSL 1056
#define XSTR 136   // x row stride in shorts (272 B, 16B-aligned rows)
#define HSTR 40    // hT row stride in shorts (80 B: 16B-aligned)

typedef __attribute__((ext_vector_type(8))) short  short8;   // 8 x bf16 MFMA A/B frag (4 VGPR)
typedef __attribute__((ext_vector_type(4))) float  floatx4;  // MFMA C/D frag (4 VGPR)
typedef __attribute__((ext_vector_type(2))) unsigned uint2v;

__device__ __forceinline__ short f2bf(float f) {             // scalar RNE (prep kernel only)
  union { float f; unsigned u; } v; v.f = f;
  unsigned r = (v.u + 0x7fffu + ((v.u >> 16) & 1u)) >> 16;
  return (short)(unsigned short)r;
}
// HW packed fp32->bf16 (RNE): plain VALU op, safe in inline asm
__device__ __forceinline__ unsigned pk2(float a, float b) {
  unsigned r; asm("v_cvt_pk_bf16_f32 %0, %1, %2" : "=v"(r) : "v"(a), "v"(b)); return r;
}
__device__ __forceinline__ float exp2_hw(float x) {
#if __has_builtin(__builtin_amdgcn_exp2f)
  return __builtin_amdgcn_exp2f(x);
#else
  return exp2f(x);
#endif
}
__device__ __forceinline__ float rcp_hw(float x) {
#if __has_builtin(__builtin_amdgcn_rcpf)
  return __builtin_amdgcn_rcpf(x);
#else
  return 1.0f / x;
#endif
}
__device__ __forceinline__ float elu1(float v) { return v > 0.f ? v : __expf(v) - 1.f; }
__device__ __forceinline__ floatx4 mfma16(short8 a, short8 b, floatx4 c) {
  return __builtin_amdgcn_mfma_f32_16x16x32_bf16(a, b, c, 0, 0, 0);
}

// ws layout (bf16): [0,8192) embT[e][k] (k<40 Wv, else Wp) | [8192,24576) wT0[e][k] | [24576,40960) wT1[e][k]
// Total: 40960 shorts = exactly 81920 B. DO NOT EXCEED (ws_size appears to be 80 KiB).
__global__ void prep_weights(const float* __restrict__ Wv, const float* __restrict__ Wp,
                             const float* __restrict__ w0, const float* __restrict__ w1,
                             short* __restrict__ ws) {
  int idx = blockIdx.x * 256 + threadIdx.x;          // 160 blocks x 256 = 40960
  if (idx < 8192) {
    int e = idx >> 6, k = idx & 63;
    float v = (k < 40) ? Wv[(size_t)k * EMB + e] : Wp[(size_t)(k - 40) * EMB + e];
    ws[idx] = f2bf(v);
  } else if (idx < 24576) {
    int t = idx - 8192; int e = t >> 7, k = t & 127;
    ws[idx] = f2bf(w0[(size_t)k * EMB + e]);
  } else {
    int t = idx - 24576; int e = t >> 7, k = t & 127;
    ws[idx] = f2bf(w1[(size_t)k * EMB + e]);
  }
}

__global__ __launch_bounds__(256, 6) void gnn_fused(
    const float* __restrict__ obs,
    const float* __restrict__ bv, const float* __restrict__ bp,
    const float* __restrict__ as0, const float* __restrict__ ad0,
    const float* __restrict__ as1, const float* __restrict__ ad1,
    const short* __restrict__ wsb,
    float* __restrict__ out)
{
  __shared__ __align__(16) short s_x[32 * XSTR];       // 8704 B: x[token][e]
  __shared__ __align__(16) short s_h[4 * 32 * HSTR];   // 10240 B: 4 wave-private hT quarters

  const int tid  = threadIdx.x;
  const int lane = tid & 63;
  const int wv   = tid >> 6;      // 0..3 = head; e-rows [32wv,32wv+32); m-tiles {2wv,2wv+1}
  const int col  = lane & 15;
  const int quad = lane >> 4;

  short* hbase = &s_h[wv * 1280];               // own hT quarter: [32 e-loc][HSTR]
  const short8  z8 = {0,0,0,0,0,0,0,0};
  const floatx4 fz = {0.f,0.f,0.f,0.f};

  for (int j = 0; j < 2; ++j) {
    const size_t b = (size_t)blockIdx.x * 2 + j;
    const float* orow = obs + b * OBSL;

    __syncthreads();                            // barJ: prev item's s_x reads done before new writes

    // ---------------- alive mask (wave-uniform), pad, scatter (proven v12 pieces) ----------------
    unsigned m32; float invc;
    {
      float araw = (lane < NTOK) ? orow[1024 + lane] : 0.f;
      bool alv = (lane < NTOK) && (araw >= 0.5f);
      unsigned long long m = __ballot(alv);
      int cnt = __popcll(m);
      unsigned mm = (unsigned)m;
      if (cnt == 0) { mm = 0xFFFFFFFFu; cnt = NTOK; }
      m32 = mm; invc = 1.f / (float)cnt;
    }

    {                                           // complement pad: veh rows cols [40,64), ped rows cols [0,40)
      int idx = tid; int r = -1, k = 0;
      if (idx < 48)       { r = (idx * 171) >> 9;  k = 40 + (idx - r * 3) * 8; }       // /3 magic (idx<48)
      else if (idx < 128) { int t2 = idx - 48; int q5 = (t2 * 205) >> 10; r = 16 + q5; k = (t2 - q5 * 5) * 8; } // /5 magic (t2<80)
      if (r >= 0) *(short8*)&s_x[r * XSTR + k] = z8;
    }
    {                                           // scatter: 256 float4, 64 per wave; disjoint from pad
      int i4 = wv * 64 + lane;
      float4 v = *(const float4*)&orow[i4 * 4];
      int r, k;
      if (i4 < 160) { r = (i4 * 205) >> 11;  k = (i4 - r * 10) * 4; }              // /10 magic (i4<160)
      else { int t2 = i4 - 160; int q6 = (t2 * 171) >> 10; r = 16 + q6; k = 40 + (t2 - q6 * 6) * 4; } // /6 magic (t2<96)
      uint2v u; u.x = pk2(v.x, v.y); u.y = pk2(v.z, v.w);
      *(uint2v*)&s_x[r * XSTR + k] = u;
    }
    __syncthreads();                            // barS: pad+scatter -> Bxin reads

    // ---------------- P1: embed D[e][tok] (LDS-staged, proven v11 path) ----------------
    {
      short8 Bxin[2][2];                        // full K=64 of x_in
      #pragma unroll
      for (int nt = 0; nt < 2; ++nt)
        #pragma unroll
        for (int kt = 0; kt < 2; ++kt)
          Bxin[nt][kt] = *(const short8*)&s_x[(nt * 16 + col) * XSTR + kt * 32 + quad * 8];
      __syncthreads();                          // barX: Bxin reads -> embed writes
      const short* embT = wsb;
      #pragma unroll
      for (int mi = 0; mi < 2; ++mi) {
        const int mtE = wv * 2 + mi;
        short8 A0 = *(const short8*)&embT[(mtE * 16 + col) * 64 + quad * 8];
        short8 A1 = *(const short8*)&embT[(mtE * 16 + col) * 64 + 32 + quad * 8];
        float4 bv4 = *(const float4*)&bv[mtE * 16 + quad * 4];
        float4 bp4 = *(const float4*)&bp[mtE * 16 + quad * 4];
        #pragma unroll
        for (int nt = 0; nt < 2; ++nt) {
          floatx4 acc = fz;
          acc = mfma16(A0, Bxin[nt][0], acc);
          acc = mfma16(A1, Bxin[nt][1], acc);
          float4 bb = nt ? bp4 : bv4;
          uint2v u; u.x = pk2(acc[0] + bb.x, acc[1] + bb.y); u.y = pk2(acc[2] + bb.z, acc[3] + bb.w);
          *(uint2v*)&s_x[(nt * 16 + col) * XSTR + mtE * 16 + quad * 4] = u;
        }
      }
    }

    // ---------------- GAT layers ----------------
    for (int L = 0; L < 2; ++L) {
      const short* wT  = wsb + 8192 + L * 16384;
      const float* gas = L ? as1 : as0;
      const float* gad = L ? ad1 : ad0;

      __syncthreads();                          // barG: x writes (embed / L0 epilogue) -> GEMM reads

      // hT GEMM, acc-major (proven v9-v12): 2 m-tiles accumulate across K
      floatx4 acc[2][2];
      #pragma unroll
      for (int mi = 0; mi < 2; ++mi) { acc[mi][0] = fz; acc[mi][1] = fz; }
      #pragma unroll
      for (int kt = 0; kt < 4; ++kt) {
        short8 B0 = *(const short8*)&s_x[(col) * XSTR + kt * 32 + quad * 8];
        short8 B1 = *(const short8*)&s_x[(16 + col) * XSTR + kt * 32 + quad * 8];
        #pragma unroll
        for (int mi = 0; mi < 2; ++mi) {
          const int mt = wv * 2 + mi;
          short8 A = *(const short8*)&wT[(mt * 16 + col) * 128 + kt * 32 + quad * 8];
          acc[mi][0] = mfma16(A, B0, acc[mi][0]);
          acc[mi][1] = mfma16(A, B1, acc[mi][1]);
        }
      }

      // alpha partials (own head)
      float psrc[2], pdst[2];
      psrc[0] = 0.f; psrc[1] = 0.f; pdst[0] = 0.f; pdst[1] = 0.f;
      #pragma unroll
      for (int mi = 0; mi < 2; ++mi) {
        const int mt = wv * 2 + mi;
        float4 cs = *(const float4*)&gas[mt * 16 + quad * 4];
        float4 cd = *(const float4*)&gad[mt * 16 + quad * 4];
        #pragma unroll
        for (int nt = 0; nt < 2; ++nt) {
          floatx4 a = acc[mi][nt];
          psrc[nt] += a[0]*cs.x + a[1]*cs.y + a[2]*cs.z + a[3]*cs.w;
          pdst[nt] += a[0]*cd.x + a[1]*cd.y + a[2]*cd.z + a[3]*cd.w;
        }
      }

      // hT writes into own (wave-private) quarter — same-wave ordering only
      #pragma unroll
      for (int mi = 0; mi < 2; ++mi) {
        const int rowloc = mi * 16 + quad * 4;  // e-local row within quarter
        #pragma unroll
        for (int nt = 0; nt < 2; ++nt) {
          floatx4 a = acc[mi][nt];
          unsigned u01 = pk2(a[0], a[1]);
          unsigned u23 = pk2(a[2], a[3]);
          unsigned short* hrow = (unsigned short*)&hbase[rowloc * HSTR + nt * 16 + col];
          hrow[0]        = (unsigned short)u01;
          hrow[HSTR]     = (unsigned short)(u01 >> 16);
          hrow[2 * HSTR] = (unsigned short)u23;
          hrow[3 * HSTR] = (unsigned short)(u23 >> 16);
        }
      }

      // full per-token alpha in every lane (token = nt*16 + col), exp2 domain
      #pragma unroll
      for (int nt = 0; nt < 2; ++nt) {
        float vs = psrc[nt]; vs += __shfl_xor(vs, 16); vs += __shfl_xor(vs, 32);
        psrc[nt] = vs * 1.44269504088896340736f;
        float vd = pdst[nt]; vd += __shfl_xor(vd, 16); vd += __shfl_xor(vd, 32);
        pdst[nt] = vd * 1.44269504088896340736f;
      }

      // softmax (own head), PV B-frag layout: lane owns (i = ii*16+col, key = quad*8+jj)
      short8 pf[2];
      {
        float vsel = (quad >> 1) ? pdst[1] : pdst[0];
        float ad8[8];
        #pragma unroll
        for (int jj = 0; jj < 8; ++jj) {
          float v = __shfl(vsel, ((quad >> 1) << 5) + ((quad & 1) << 3) + jj);
          bool alive = (m32 >> (quad * 8 + jj)) & 1u;        // SGPR mask test (proven v12)
          ad8[jj] = alive ? v : -1e30f;                      // dead keys -> exp2 -> 0
        }
        #pragma unroll
        for (int ii = 0; ii < 2; ++ii) {
          float ai = psrc[ii];
          float ev[8]; float sum = 0.f;
          #pragma unroll
          for (int jj = 0; jj < 8; ++jj) {
            float e = ai + ad8[jj];
            e = fmaxf(e, 0.2f * e);                          // leaky-relu (commutes with log2e scale)
            float p = exp2_hw(e);
            ev[jj] = p; sum += p;
          }
          sum += __shfl_xor(sum, 16);
          sum += __shfl_xor(sum, 32);
          float inv = rcp_hw(sum);
          union { unsigned u4[4]; short8 s; } pu;
          #pragma unroll
          for (int p2 = 0; p2 < 4; ++p2) pu.u4[p2] = pk2(ev[2*p2] * inv, ev[2*p2+1] * inv);
          pf[ii] = pu.s;
        }
      }

      // PV A-frags from own quarter (same-wave), then barE before x_next writes
      short8 Ah[2];
      #pragma unroll
      for (int mt2 = 0; mt2 < 2; ++mt2)
        Ah[mt2] = *(const short8*)&hbase[(mt2 * 16 + col) * HSTR + quad * 8];
      if (L == 0) __syncthreads();              // barE: ALL waves' GEMM x-reads done -> x_next writes

      #pragma unroll
      for (int mt2 = 0; mt2 < 2; ++mt2) {
        floatx4 po[2];
        #pragma unroll
        for (int nt = 0; nt < 2; ++nt) {
          po[nt] = mfma16(Ah[mt2], pf[nt], fz);
        }
        const int ecol = wv * 32 + mt2 * 16 + quad * 4;  // global e
        if (L == 0) {
          #pragma unroll
          for (int nt = 0; nt < 2; ++nt) {
            uint2v u;
            u.x = pk2(elu1(po[nt][0]), elu1(po[nt][1]));
            u.y = pk2(elu1(po[nt][2]), elu1(po[nt][3]));
            *(uint2v*)&s_x[(nt * 16 + col) * XSTR + ecol] = u;
          }
        } else {
          float aI0 = ((m32 >> col) & 1u) ? 1.f : 0.f;         // alive of token col
          float aI1 = ((m32 >> (16 + col)) & 1u) ? 1.f : 0.f;  // alive of token 16+col
          #pragma unroll
          for (int r = 0; r < 4; ++r) {
            float s = elu1(po[0][r]) * aI0 + elu1(po[1][r]) * aI1;
            s += __shfl_xor(s, 1); s += __shfl_xor(s, 2);
            s += __shfl_xor(s, 4); s += __shfl_xor(s, 8);
            if (col == 0) out[b * EMB + ecol + r] = s * invc;  // direct store (proven path)
          }
        }
      }
    }
  }
}

extern "C" void kernel_launch(void* const* d_in, const int* in_sizes, int n_in,
                              void* d_out, int out_size, void* d_ws, size_t ws_size,
                              hipStream_t stream) {
  const float* obs = (const float*)d_in[0];
  const float* Wv  = (const float*)d_in[1];
  const float* bv  = (const float*)d_in[2];
  const float* Wp  = (const float*)d_in[3];
  const float* bp  = (const float*)d_in[4];
  const float* w0  = (const float*)d_in[5];
  const float* as0 = (const float*)d_in[6];
  const float* ad0 = (const float*)d_in[7];
  const float* w1  = (const float*)d_in[8];
  const float* as1 = (const float*)d_in[9];
  const float* ad1 = (const float*)d_in[10];
  float* out = (float*)d_out;
  short* wsb = (short*)d_ws;                      // uses exactly 80 KiB

  int Bn = in_sizes[0] / OBSL;                    // 4096
  prep_weights<<<160, 256, 0, stream>>>(Wv, Wp, w0, w1, wsb);
  gnn_fused<<<Bn / 2, 256, 0, stream>>>(obs, bv, bp, as0, ad0, as1, ad1, wsb, out);
}

// Round 13
// 132.681 us; speedup vs baseline: 1.4238x; 1.4238x over previous
//
#include <hip/hip_runtime.h>

// GNNCriticEncoder fused kernel v15 (MI355X / gfx950)
// v14 post-mortem: PASSED (body now correctness-proven) but spilled massively
// (FETCH 73MB + WRITE 84MB scratch, occ 43%, 120us): the j=0,1 sequential loop has
// compile-time trip count 2 -> compiler unrolled + software-pipelined across items,
// recreating v12's two-items-live register footprint. Rule confirmed twice: ANY form
// of 2-items-in-flight (explicit v12, compiler-created v14) blows the ~64-VGPR budget.
// v15 = v14's proven body, ONE item per block (grid 4096, no j-loop):
//  - separate s_h (no x<->hT alias) -> alias barriers gone: 5 barriers/item (v11: 8)
//  - complement-pad merged with scatter (one epoch, one fence)
//  - SGPR ballot-mask alive tests (no shuffles)
//  - per-item register state = v11's (~55 incl AGPRs) -> no spill.
// ws = exactly 81920 B (do not exceed).

#define NTOK 32
#define EMB  128
#define OBSL 1056
#define XSTR 136   // x row stride in shorts (272 B, 16B-aligned rows)
#define HSTR 40    // hT row stride in shorts (80 B: 16B-aligned)

typedef __attribute__((ext_vector_type(8))) short  short8;   // 8 x bf16 MFMA A/B frag (4 VGPR)
typedef __attribute__((ext_vector_type(4))) float  floatx4;  // MFMA C/D frag (4 VGPR)
typedef __attribute__((ext_vector_type(2))) unsigned uint2v;

__device__ __forceinline__ short f2bf(float f) {             // scalar RNE (prep kernel only)
  union { float f; unsigned u; } v; v.f = f;
  unsigned r = (v.u + 0x7fffu + ((v.u >> 16) & 1u)) >> 16;
  return (short)(unsigned short)r;
}
// HW packed fp32->bf16 (RNE): plain VALU op, safe in inline asm
__device__ __forceinline__ unsigned pk2(float a, float b) {
  unsigned r; asm("v_cvt_pk_bf16_f32 %0, %1, %2" : "=v"(r) : "v"(a), "v"(b)); return r;
}
__device__ __forceinline__ float exp2_hw(float x) {
#if __has_builtin(__builtin_amdgcn_exp2f)
  return __builtin_amdgcn_exp2f(x);
#else
  return exp2f(x);
#endif
}
__device__ __forceinline__ float rcp_hw(float x) {
#if __has_builtin(__builtin_amdgcn_rcpf)
  return __builtin_amdgcn_rcpf(x);
#else
  return 1.0f / x;
#endif
}
__device__ __forceinline__ float elu1(float v) { return v > 0.f ? v : __expf(v) - 1.f; }
__device__ __forceinline__ floatx4 mfma16(short8 a, short8 b, floatx4 c) {
  return __builtin_amdgcn_mfma_f32_16x16x32_bf16(a, b, c, 0, 0, 0);
}

// ws layout (bf16): [0,8192) embT[e][k] (k<40 Wv, else Wp) | [8192,24576) wT0[e][k] | [24576,40960) wT1[e][k]
// Total: 40960 shorts = exactly 81920 B. DO NOT EXCEED (ws_size appears to be 80 KiB).
__global__ void prep_weights(const float* __restrict__ Wv, const float* __restrict__ Wp,
                             const float* __restrict__ w0, const float* __restrict__ w1,
                             short* __restrict__ ws) {
  int idx = blockIdx.x * 256 + threadIdx.x;          // 160 blocks x 256 = 40960
  if (idx < 8192) {
    int e = idx >> 6, k = idx & 63;
    float v = (k < 40) ? Wv[(size_t)k * EMB + e] : Wp[(size_t)(k - 40) * EMB + e];
    ws[idx] = f2bf(v);
  } else if (idx < 24576) {
    int t = idx - 8192; int e = t >> 7, k = t & 127;
    ws[idx] = f2bf(w0[(size_t)k * EMB + e]);
  } else {
    int t = idx - 24576; int e = t >> 7, k = t & 127;
    ws[idx] = f2bf(w1[(size_t)k * EMB + e]);
  }
}

__global__ __launch_bounds__(256, 6) void gnn_fused(
    const float* __restrict__ obs,
    const float* __restrict__ bv, const float* __restrict__ bp,
    const float* __restrict__ as0, const float* __restrict__ ad0,
    const float* __restrict__ as1, const float* __restrict__ ad1,
    const short* __restrict__ wsb,
    float* __restrict__ out)
{
  __shared__ __align__(16) short s_x[32 * XSTR];       // 8704 B: x[token][e]
  __shared__ __align__(16) short s_h[4 * 32 * HSTR];   // 10240 B: 4 wave-private hT quarters

  const int tid  = threadIdx.x;
  const int lane = tid & 63;
  const int wv   = tid >> 6;      // 0..3 = head; e-rows [32wv,32wv+32); m-tiles {2wv,2wv+1}
  const int col  = lane & 15;
  const int quad = lane >> 4;
  const size_t b = blockIdx.x;

  const float* orow = obs + b * OBSL;
  short* hbase = &s_h[wv * 1280];               // own hT quarter: [32 e-loc][HSTR]
  const short8  z8 = {0,0,0,0,0,0,0,0};
  const floatx4 fz = {0.f,0.f,0.f,0.f};

  // ---------------- alive mask (wave-uniform), pad, scatter (proven v12/v14 pieces) ----------------
  unsigned m32; float invc;
  {
    float araw = (lane < NTOK) ? orow[1024 + lane] : 0.f;
    bool alv = (lane < NTOK) && (araw >= 0.5f);
    unsigned long long m = __ballot(alv);
    int cnt = __popcll(m);
    unsigned mm = (unsigned)m;
    if (cnt == 0) { mm = 0xFFFFFFFFu; cnt = NTOK; }
    m32 = mm; invc = 1.f / (float)cnt;
  }

  {                                             // complement pad: veh rows cols [40,64), ped rows cols [0,40)
    int idx = tid; int r = -1, k = 0;
    if (idx < 48)       { r = (idx * 171) >> 9;  k = 40 + (idx - r * 3) * 8; }       // /3 magic (idx<48)
    else if (idx < 128) { int t2 = idx - 48; int q5 = (t2 * 205) >> 10; r = 16 + q5; k = (t2 - q5 * 5) * 8; } // /5 magic (t2<80)
    if (r >= 0) *(short8*)&s_x[r * XSTR + k] = z8;
  }
  {                                             // scatter: 256 float4, 64 per wave; disjoint from pad
    int i4 = wv * 64 + lane;
    float4 v = *(const float4*)&orow[i4 * 4];
    int r, k;
    if (i4 < 160) { r = (i4 * 205) >> 11;  k = (i4 - r * 10) * 4; }              // /10 magic (i4<160)
    else { int t2 = i4 - 160; int q6 = (t2 * 171) >> 10; r = 16 + q6; k = 40 + (t2 - q6 * 6) * 4; } // /6 magic (t2<96)
    uint2v u; u.x = pk2(v.x, v.y); u.y = pk2(v.z, v.w);
    *(uint2v*)&s_x[r * XSTR + k] = u;
  }
  __syncthreads();                              // barS: pad+scatter -> Bxin reads

  // ---------------- P1: embed D[e][tok] (LDS-staged, proven path) ----------------
  {
    short8 Bxin[2][2];                          // full K=64 of x_in
    #pragma unroll
    for (int nt = 0; nt < 2; ++nt)
      #pragma unroll
      for (int kt = 0; kt < 2; ++kt)
        Bxin[nt][kt] = *(const short8*)&s_x[(nt * 16 + col) * XSTR + kt * 32 + quad * 8];
    __syncthreads();                            // barX: Bxin reads -> embed writes
    const short* embT = wsb;
    #pragma unroll
    for (int mi = 0; mi < 2; ++mi) {
      const int mtE = wv * 2 + mi;
      short8 A0 = *(const short8*)&embT[(mtE * 16 + col) * 64 + quad * 8];
      short8 A1 = *(const short8*)&embT[(mtE * 16 + col) * 64 + 32 + quad * 8];
      float4 bv4 = *(const float4*)&bv[mtE * 16 + quad * 4];
      float4 bp4 = *(const float4*)&bp[mtE * 16 + quad * 4];
      #pragma unroll
      for (int nt = 0; nt < 2; ++nt) {
        floatx4 acc = fz;
        acc = mfma16(A0, Bxin[nt][0], acc);
        acc = mfma16(A1, Bxin[nt][1], acc);
        float4 bb = nt ? bp4 : bv4;
        uint2v u; u.x = pk2(acc[0] + bb.x, acc[1] + bb.y); u.y = pk2(acc[2] + bb.z, acc[3] + bb.w);
        *(uint2v*)&s_x[(nt * 16 + col) * XSTR + mtE * 16 + quad * 4] = u;
      }
    }
  }

  // ---------------- GAT layers ----------------
  for (int L = 0; L < 2; ++L) {
    const short* wT  = wsb + 8192 + L * 16384;
    const float* gas = L ? as1 : as0;
    const float* gad = L ? ad1 : ad0;

    __syncthreads();                            // barG: x writes (embed / L0 epilogue) -> GEMM reads

    // hT GEMM, acc-major (proven): 2 m-tiles accumulate across K
    floatx4 acc[2][2];
    #pragma unroll
    for (int mi = 0; mi < 2; ++mi) { acc[mi][0] = fz; acc[mi][1] = fz; }
    #pragma unroll
    for (int kt = 0; kt < 4; ++kt) {
      short8 B0 = *(const short8*)&s_x[(col) * XSTR + kt * 32 + quad * 8];
      short8 B1 = *(const short8*)&s_x[(16 + col) * XSTR + kt * 32 + quad * 8];
      #pragma unroll
      for (int mi = 0; mi < 2; ++mi) {
        const int mt = wv * 2 + mi;
        short8 A = *(const short8*)&wT[(mt * 16 + col) * 128 + kt * 32 + quad * 8];
        acc[mi][0] = mfma16(A, B0, acc[mi][0]);
        acc[mi][1] = mfma16(A, B1, acc[mi][1]);
      }
    }

    // alpha partials (own head)
    float psrc[2], pdst[2];
    psrc[0] = 0.f; psrc[1] = 0.f; pdst[0] = 0.f; pdst[1] = 0.f;
    #pragma unroll
    for (int mi = 0; mi < 2; ++mi) {
      const int mt = wv * 2 + mi;
      float4 cs = *(const float4*)&gas[mt * 16 + quad * 4];
      float4 cd = *(const float4*)&gad[mt * 16 + quad * 4];
      #pragma unroll
      for (int nt = 0; nt < 2; ++nt) {
        floatx4 a = acc[mi][nt];
        psrc[nt] += a[0]*cs.x + a[1]*cs.y + a[2]*cs.z + a[3]*cs.w;
        pdst[nt] += a[0]*cd.x + a[1]*cd.y + a[2]*cd.z + a[3]*cd.w;
      }
    }

    // hT writes into own (wave-private) quarter — same-wave ordering only, no barrier
    #pragma unroll
    for (int mi = 0; mi < 2; ++mi) {
      const int rowloc = mi * 16 + quad * 4;    // e-local row within quarter
      #pragma unroll
      for (int nt = 0; nt < 2; ++nt) {
        floatx4 a = acc[mi][nt];
        unsigned u01 = pk2(a[0], a[1]);
        unsigned u23 = pk2(a[2], a[3]);
        unsigned short* hrow = (unsigned short*)&hbase[rowloc * HSTR + nt * 16 + col];
        hrow[0]        = (unsigned short)u01;
        hrow[HSTR]     = (unsigned short)(u01 >> 16);
        hrow[2 * HSTR] = (unsigned short)u23;
        hrow[3 * HSTR] = (unsigned short)(u23 >> 16);
      }
    }

    // full per-token alpha in every lane (token = nt*16 + col), exp2 domain
    #pragma unroll
    for (int nt = 0; nt < 2; ++nt) {
      float vs = psrc[nt]; vs += __shfl_xor(vs, 16); vs += __shfl_xor(vs, 32);
      psrc[nt] = vs * 1.44269504088896340736f;
      float vd = pdst[nt]; vd += __shfl_xor(vd, 16); vd += __shfl_xor(vd, 32);
      pdst[nt] = vd * 1.44269504088896340736f;
    }

    // softmax (own head), PV B-frag layout: lane owns (i = ii*16+col, key = quad*8+jj)
    short8 pf[2];
    {
      float vsel = (quad >> 1) ? pdst[1] : pdst[0];
      float ad8[8];
      #pragma unroll
      for (int jj = 0; jj < 8; ++jj) {
        float v = __shfl(vsel, ((quad >> 1) << 5) + ((quad & 1) << 3) + jj);
        bool alive = (m32 >> (quad * 8 + jj)) & 1u;        // SGPR mask test
        ad8[jj] = alive ? v : -1e30f;                      // dead keys -> exp2 -> 0
      }
      #pragma unroll
      for (int ii = 0; ii < 2; ++ii) {
        float ai = psrc[ii];
        float ev[8]; float sum = 0.f;
        #pragma unroll
        for (int jj = 0; jj < 8; ++jj) {
          float e = ai + ad8[jj];
          e = fmaxf(e, 0.2f * e);                          // leaky-relu (commutes with log2e scale)
          float p = exp2_hw(e);
          ev[jj] = p; sum += p;
        }
        sum += __shfl_xor(sum, 16);
        sum += __shfl_xor(sum, 32);
        float inv = rcp_hw(sum);
        union { unsigned u4[4]; short8 s; } pu;
        #pragma unroll
        for (int p2 = 0; p2 < 4; ++p2) pu.u4[p2] = pk2(ev[2*p2] * inv, ev[2*p2+1] * inv);
        pf[ii] = pu.s;
      }
    }

    // PV A-frags from own quarter (same-wave), then barE before x_next writes
    short8 Ah[2];
    #pragma unroll
    for (int mt2 = 0; mt2 < 2; ++mt2)
      Ah[mt2] = *(const short8*)&hbase[(mt2 * 16 + col) * HSTR + quad * 8];
    if (L == 0) __syncthreads();                // barE: ALL waves' GEMM x-reads done -> x_next writes

    #pragma unroll
    for (int mt2 = 0; mt2 < 2; ++mt2) {
      floatx4 po[2];
      #pragma unroll
      for (int nt = 0; nt < 2; ++nt) {
        po[nt] = mfma16(Ah[mt2], pf[nt], fz);
      }
      const int ecol = wv * 32 + mt2 * 16 + quad * 4;  // global e
      if (L == 0) {
        #pragma unroll
        for (int nt = 0; nt < 2; ++nt) {
          uint2v u;
          u.x = pk2(elu1(po[nt][0]), elu1(po[nt][1]));
          u.y = pk2(elu1(po[nt][2]), elu1(po[nt][3]));
          *(uint2v*)&s_x[(nt * 16 + col) * XSTR + ecol] = u;
        }
      } else {
        float aI0 = ((m32 >> col) & 1u) ? 1.f : 0.f;         // alive of token col
        float aI1 = ((m32 >> (16 + col)) & 1u) ? 1.f : 0.f;  // alive of token 16+col
        #pragma unroll
        for (int r = 0; r < 4; ++r) {
          float s = elu1(po[0][r]) * aI0 + elu1(po[1][r]) * aI1;
          s += __shfl_xor(s, 1); s += __shfl_xor(s, 2);
          s += __shfl_xor(s, 4); s += __shfl_xor(s, 8);
          if (col == 0) out[b * EMB + ecol + r] = s * invc;  // direct store (proven path)
        }
      }
    }
  }
}

extern "C" void kernel_launch(void* const* d_in, const int* in_sizes, int n_in,
                              void* d_out, int out_size, void* d_ws, size_t ws_size,
                              hipStream_t stream) {
  const float* obs = (const float*)d_in[0];
  const float* Wv  = (const float*)d_in[1];
  const float* bv  = (const float*)d_in[2];
  const float* Wp  = (const float*)d_in[3];
  const float* bp  = (const float*)d_in[4];
  const float* w0  = (const float*)d_in[5];
  const float* as0 = (const float*)d_in[6];
  const float* ad0 = (const float*)d_in[7];
  const float* w1  = (const float*)d_in[8];
  const float* as1 = (const float*)d_in[9];
  const float* ad1 = (const float*)d_in[10];
  float* out = (float*)d_out;
  short* wsb = (short*)d_ws;                      // uses exactly 80 KiB

  int Bn = in_sizes[0] / OBSL;                    // 4096
  prep_weights<<<160, 256, 0, stream>>>(Wv, Wp, w0, w1, wsb);
  gnn_fused<<<Bn, 256, 0, stream>>>(obs, bv, bp, as0, ad0, as1, ad1, wsb, out);
}